// Round 16
// baseline (172.109 us; speedup 1.0000x reference)
//
#include <hip/hip_runtime.h>
#include <hip/hip_bf16.h>
#include <stdint.h>

#define BATCH 8
#define CCH   512
#define NHD   8
#define HD    64
#define LLEN  4096
#define M1    1536

typedef __bf16 bf16x8 __attribute__((ext_vector_type(8)));
typedef __bf16 bf16x4 __attribute__((ext_vector_type(4)));
typedef float  f32x4  __attribute__((ext_vector_type(4)));

__device__ __forceinline__ f32x4 mfma16(bf16x8 a, bf16x8 b, f32x4 c) {
  return __builtin_amdgcn_mfma_f32_16x16x32_bf16(a, b, c, 0, 0, 0);
}

__device__ __forceinline__ void gload_lds16(const void* g, void* l) {
  __builtin_amdgcn_global_load_lds(
      (const __attribute__((address_space(1))) uint32_t*)(uintptr_t)g,
      (__attribute__((address_space(3))) uint32_t*)(uintptr_t)l,
      16, 0, 0);
}

// ---------------- pack weights/biases to bf16 ----------------
__global__ void pack_w(const float* __restrict__ wq, const float* __restrict__ wk,
                       const float* __restrict__ wv, const float* __restrict__ wo,
                       const float* __restrict__ bq, const float* __restrict__ bk,
                       const float* __restrict__ bv,
                       __bf16* __restrict__ wqkvb, __bf16* __restrict__ wob,
                       float* __restrict__ biasq) {
  const int n = M1 * CCH + CCH * CCH + M1;
  for (int i = blockIdx.x * blockDim.x + threadIdx.x; i < n; i += gridDim.x * blockDim.x) {
    if (i < M1 * CCH) {
      int r = i >> 9, c = i & 511;
      float v = (r < 512) ? wq[r * 512 + c]
              : (r < 1024) ? wk[(r - 512) * 512 + c]
                           : wv[(r - 1024) * 512 + c];
      wqkvb[i] = (__bf16)v;
    } else if (i < M1 * CCH + CCH * CCH) {
      int j = i - M1 * CCH;
      wob[j] = (__bf16)wo[j];
    } else {
      int j = i - M1 * CCH - CCH * CCH;
      biasq[j] = (j < 512) ? bq[j] : (j < 1024) ? bk[j - 512] : bv[j - 1024];
    }
  }
}

// ---------------- x [b][C][L] fp32 -> xt [b][L][C] bf16 (64x64 tiles) ----------------
__global__ __launch_bounds__(256) void transpose_x(const float* __restrict__ x,
                                                   __bf16* __restrict__ xt) {
  __shared__ float tile[64][65];
  const int b = blockIdx.z, c0 = blockIdx.y * 64, l0 = blockIdx.x * 64;
  const int t = threadIdx.x;
  const int lq = (t & 15) * 4, cr = t >> 4;
  const float* xp = x + ((size_t)b * CCH + c0) * LLEN + l0;
#pragma unroll
  for (int q = 0; q < 4; ++q) {
    const int c = cr + q * 16;
    float4 v = *(const float4*)(xp + (size_t)c * LLEN + lq);
    tile[c][lq + 0] = v.x;
    tile[c][lq + 1] = v.y;
    tile[c][lq + 2] = v.z;
    tile[c][lq + 3] = v.w;
  }
  __syncthreads();
  __bf16* xo = xt + ((size_t)b * LLEN + l0) * CCH + c0;
  const int c8 = (t & 7) * 8, lr = t >> 3;
#pragma unroll
  for (int p = 0; p < 2; ++p) {
    const int l = lr + p * 32;
    bf16x8 o;
#pragma unroll
    for (int i = 0; i < 8; ++i) o[i] = (__bf16)tile[c8 + i][l];
    *(bf16x8*)(xo + (size_t)l * CCH + c8) = o;
  }
}

// ==== 256x128 GEMM: wave-tile 128x64 (B-frags reg-reused over 2 m-subtiles) ====
// LDS/FLOP: 34 B/KFLOP vs 92 at 64x64 wave-tiles (the r15-diagnosed LDS-BW wall).
// Triple-buffered 72KB (3x24KB: A 16KB + B 8KB per buffer), prefetch dist 2,
// counted vmcnt(6) (= 6 gloads/tile in flight), r15 0-conflict swizzle, 2 blk/CU.
#define STG256(tt, bufidx)                                                   \
  {                                                                          \
    const __bf16* As_ = Ag + (tt) * 32;                                      \
    const __bf16* Bs_ = Bg + (tt) * 32;                                      \
    __bf16* dA = lds + (bufidx) * 12288;                                     \
    __bf16* dB = dA + 8192;                                                  \
    gload_lds16(As_ + srcOff,              dA + tid * 8);                    \
    gload_lds16(As_ + srcOff + 64 * CCH,   dA + tid * 8 + 2048);             \
    gload_lds16(As_ + srcOff + 128 * CCH,  dA + tid * 8 + 4096);             \
    gload_lds16(As_ + srcOff + 192 * CCH,  dA + tid * 8 + 6144);             \
    gload_lds16(Bs_ + srcOff,              dB + tid * 8);                    \
    gload_lds16(Bs_ + srcOff + 64 * CCH,   dB + tid * 8 + 2048);             \
  }

template <int EPI>
__global__ __launch_bounds__(256, 2) void gemm256x(
    const __bf16* __restrict__ A, const __bf16* __restrict__ Bm,
    const float* __restrict__ bias,
    __bf16* __restrict__ qt, __bf16* __restrict__ kcm, __bf16* __restrict__ vcm,
    float* __restrict__ out) {
  __shared__ __attribute__((aligned(16))) __bf16 lds[3 * 12288];  // 72KB
  const int b  = blockIdx.z;
  const int n0 = blockIdx.x * 128;
  const int m0 = blockIdx.y * 256;
  const int tid = threadIdx.x;
  const int ll = tid & 63, w = tid >> 6;  // 4 waves: 2M x 2N
  const int wr = w >> 1, wc = w & 1;      // wave tile 128m x 64n
  const int lhi = ll >> 4, llo = ll & 15;

  // frag read offsets (r15 swizzle: row's chunk c at slot c ^ ((row>>1)&3))
  const int slotE = ((lhi ^ ((llo >> 1) & 3)) << 3);
  int aOff[8], bOff[4];
#pragma unroll
  for (int m = 0; m < 8; ++m) aOff[m] = (wr * 128 + m * 16 + llo) * 32 + slotE;
#pragma unroll
  for (int n = 0; n < 4; ++n) bOff[n] = 8192 + (wc * 64 + n * 16 + llo) * 32 + slotE;

  // staging decode (inverse swizzle); row-block offsets (64 rows) keep chunk slot
  // invariant: slot s = tid + k*256 -> row (tid>>2)+k*64, chunk (tid&3)^((row>>1)&3)
  const int r0 = tid >> 2;
  const int srcOff = r0 * CCH + (((tid & 3) ^ ((r0 >> 1) & 3)) << 3);

  const __bf16* Ag = A + (size_t)m0 * CCH;
  const __bf16* Bg = Bm + ((size_t)b * LLEN + n0) * CCH;

  f32x4 acc[8][4] = {};

  // prologue: tiles 0,1 staged; drain tile0 only (tile1's 6 loads stay in flight)
  STG256(0, 0)
  STG256(1, 1)
  asm volatile("s_waitcnt vmcnt(6)" ::: "memory");
  __builtin_amdgcn_s_barrier();
  __builtin_amdgcn_sched_barrier(0);

  int bufc = 0, bufs = 2;
  for (int t = 0; t < 16; ++t) {
    if (t < 14) STG256(t + 2, bufs)
    bf16x8 af[8], bfr[4];
    const __bf16* base = lds + bufc * 12288;
#pragma unroll
    for (int n = 0; n < 4; ++n) bfr[n] = *(const bf16x8*)(base + bOff[n]);
#pragma unroll
    for (int m = 0; m < 8; ++m) af[m] = *(const bf16x8*)(base + aOff[m]);
#pragma unroll
    for (int m = 0; m < 8; ++m)
#pragma unroll
      for (int n = 0; n < 4; ++n) acc[m][n] = mfma16(af[m], bfr[n], acc[m][n]);
    if (t < 14)       asm volatile("s_waitcnt vmcnt(6)" ::: "memory");
    else if (t == 14) asm volatile("s_waitcnt vmcnt(0)" ::: "memory");
    __builtin_amdgcn_s_barrier();
    __builtin_amdgcn_sched_barrier(0);
    bufc = (bufc == 2) ? 0 : bufc + 1;
    bufs = (bufs == 2) ? 0 : bufs + 1;
  }

  // epilogue (scalar, r8 form — measured best). m0 is a multiple of 256 so each
  // block lies entirely within one of Q/K/V.
#pragma unroll
  for (int i = 0; i < 8; ++i) {
    const int o0 = m0 + wr * 128 + i * 16 + lhi * 4;
#pragma unroll
    for (int j = 0; j < 4; ++j) {
      const int col = n0 + wc * 64 + j * 16 + llo;
      if (EPI == 0) {
        if (m0 < 512) {
          bf16x4 pk;
#pragma unroll
          for (int r = 0; r < 4; ++r) {
            float tv = acc[i][j][r] + bias[o0 + r];
            tv = tv > 0.f ? tv + 1.f : __expf(tv);
            pk[r] = (__bf16)tv;
          }
          *(bf16x4*)(qt + ((size_t)b * LLEN + col) * CCH + o0) = pk;
        } else if (m0 < 1024) {
#pragma unroll
          for (int r = 0; r < 4; ++r) {
            float tv = acc[i][j][r] + bias[o0 + r];
            tv = tv > 0.f ? tv + 1.f : __expf(tv);
            kcm[((size_t)b * CCH + (o0 - 512 + r)) * LLEN + col] = (__bf16)tv;
          }
        } else {
#pragma unroll
          for (int r = 0; r < 4; ++r)
            vcm[((size_t)b * CCH + (o0 - 1024 + r)) * LLEN + col] =
                (__bf16)(acc[i][j][r] + bias[o0 + r]);
        }
      } else {
#pragma unroll
        for (int r = 0; r < 4; ++r)
          out[((size_t)b * CCH + o0 + r) * LLEN + col] = acc[i][j][r] + bias[o0 + r];
      }
    }
  }
}

// ---------------- KV partials + fused Ksum partials (4 waves, LDS reduce) ----------------
__global__ __launch_bounds__(256) void kv_part_k(const __bf16* __restrict__ kcm,
                                                 const __bf16* __restrict__ vcm,
                                                 float* __restrict__ part,
                                                 float* __restrict__ part_ks) {
  __shared__ float red[8192];
  __shared__ float ksred[4][64];
  const int lc = blockIdx.x, bh = blockIdx.y;
  const int b = bh >> 3, h = bh & 7;
  const int tid = threadIdx.x;
  const int w = tid >> 6, ll = tid & 63, lhi = ll >> 4, llo = ll & 15;
  const __bf16* Kp = kcm + ((size_t)b * CCH + h * 64) * LLEN;
  const __bf16* Vp = vcm + ((size_t)b * CCH + h * 64) * LLEN;
  f32x4 acc[4][4];
#pragma unroll
  for (int i = 0; i < 4; ++i)
#pragma unroll
    for (int j = 0; j < 4; ++j) acc[i][j] = (f32x4){0.f, 0.f, 0.f, 0.f};
  float ks[4] = {0.f, 0.f, 0.f, 0.f};
  const int base = lc * 512 + w * 128 + lhi * 8;
#pragma unroll
  for (int kt = 0; kt < 4; ++kt) {
    const int k0 = base + kt * 32;
    bf16x8 af[4], bfr[4];
#pragma unroll
    for (int i = 0; i < 4; ++i) af[i]  = *(const bf16x8*)(Kp + (size_t)(i * 16 + llo) * LLEN + k0);
#pragma unroll
    for (int i = 0; i < 4; ++i) bfr[i] = *(const bf16x8*)(Vp + (size_t)(i * 16 + llo) * LLEN + k0);
#pragma unroll
    for (int i = 0; i < 4; ++i)
#pragma unroll
      for (int r = 0; r < 8; ++r) ks[i] += (float)af[i][r];
#pragma unroll
    for (int i = 0; i < 4; ++i)
#pragma unroll
      for (int j = 0; j < 4; ++j) acc[i][j] = mfma16(af[i], bfr[j], acc[i][j]);
  }
#pragma unroll
  for (int i = 0; i < 4; ++i) {
    float s = ks[i];
    s += __shfl_xor(s, 16);
    s += __shfl_xor(s, 32);
    if (lhi == 0) ksred[w][i * 16 + llo] = s;
  }
  if (w >= 2) {
#pragma unroll
    for (int i = 0; i < 4; ++i)
#pragma unroll
      for (int j = 0; j < 4; ++j)
        *(f32x4*)(red + (((w - 2) * 16 + i * 4 + j) << 8) + ll * 4) = acc[i][j];
  }
  __syncthreads();
  if (w < 2) {
#pragma unroll
    for (int i = 0; i < 4; ++i)
#pragma unroll
      for (int j = 0; j < 4; ++j)
        acc[i][j] += *(const f32x4*)(red + ((w * 16 + i * 4 + j) << 8) + ll * 4);
  }
  float ksv = 0.f;
  if (w == 1) ksv = ksred[0][ll] + ksred[1][ll] + ksred[2][ll] + ksred[3][ll];
  __syncthreads();
  if (w == 1) {
#pragma unroll
    for (int i = 0; i < 4; ++i)
#pragma unroll
      for (int j = 0; j < 4; ++j)
        *(f32x4*)(red + ((i * 4 + j) << 8) + ll * 4) = acc[i][j];
    part_ks[((size_t)lc * 64 + bh) * 64 + ll] = ksv;
  }
  __syncthreads();
  if (w == 0) {
    float* op = part + ((size_t)lc * 64 + bh) * 4096;
#pragma unroll
    for (int i = 0; i < 4; ++i)
#pragma unroll
      for (int j = 0; j < 4; ++j) {
        acc[i][j] += *(const f32x4*)(red + ((i * 4 + j) << 8) + ll * 4);
#pragma unroll
        for (int r = 0; r < 4; ++r) {
          int d = i * 16 + lhi * 4 + r, v = j * 16 + llo;
          op[d * 64 + v] = acc[i][j][r];
        }
      }
  }
}

// ---- merged reduction: kv (262144 elems) + ksum (4096 elems) in one launch ----
__global__ void red_k(const float* __restrict__ part, const float* __restrict__ pks,
                      float* __restrict__ kv, float* __restrict__ ksum) {
  const int bid = blockIdx.x;
  const int t = threadIdx.x;
  if (bid < 1024) {
    const int i = bid * 256 + t;
    float s = 0.f;
#pragma unroll
    for (int lc = 0; lc < 8; ++lc) s += part[(size_t)lc * 262144 + i];
    kv[i] = s;
  } else {
    const int i = (bid - 1024) * 256 + t;
    float s = 0.f;
#pragma unroll
    for (int lc = 0; lc < 8; ++lc) s += pks[(size_t)lc * 4096 + i];
    ksum[i] = s;
  }
}

// ---------------- apply: attn[b][l][h*64+v] = (sum_d Q[l,d]KV[d,v]) * Z[l] ----------------
__global__ __launch_bounds__(256) void apply_k(const __bf16* __restrict__ qt,
                                               const float* __restrict__ kv,
                                               const float* __restrict__ ksum,
                                               __bf16* __restrict__ attn) {
  __shared__ __attribute__((aligned(16))) __bf16 kvT[64 * 68];
  __shared__ float zb[256];
  const int lc = blockIdx.x, bh = blockIdx.y;
  const int b = bh >> 3, h = bh & 7;
  const int tid = threadIdx.x;
  const float* kvp = kv + (size_t)bh * 4096;
  for (int i = tid; i < 4096; i += 256) {
    int d = i >> 6, v = i & 63;
    kvT[v * 68 + d] = (__bf16)kvp[i];
  }
  const int l = lc * 256 + tid;
  const __bf16* qp = qt + ((size_t)b * LLEN + l) * CCH + h * 64;
  const float* ksp = ksum + bh * 64;
  float s = 0.f;
#pragma unroll
  for (int d8 = 0; d8 < 64; d8 += 8) {
    bf16x8 qv = *(const bf16x8*)(qp + d8);
#pragma unroll
    for (int i = 0; i < 8; ++i) s += (float)qv[i] * ksp[d8 + i];
  }
  zb[tid] = 1.0f / (s + 1e-6f);
  __syncthreads();

  const int ll = tid & 63, w = tid >> 6, lhi = ll >> 4, llo = ll & 15;
  f32x4 acc[4][4];
#pragma unroll
  for (int i = 0; i < 4; ++i)
#pragma unroll
    for (int j = 0; j < 4; ++j) acc[i][j] = (f32x4){0.f, 0.f, 0.f, 0.f};
  const __bf16* qbase = qt + ((size_t)b * LLEN + lc * 256 + w * 64) * CCH + h * 64;
#pragma unroll
  for (int kt = 0; kt < 2; ++kt) {
    const int k8 = kt * 32 + lhi * 8;
    bf16x8 af[4], bfr[4];
#pragma unroll
    for (int i = 0; i < 4; ++i)
      af[i] = *(const bf16x8*)(qbase + (size_t)(i * 16 + llo) * CCH + k8);
#pragma unroll
    for (int j = 0; j < 4; ++j) {
      const __bf16* pb = kvT + (j * 16 + llo) * 68 + k8;
      ((bf16x4*)&bfr[j])[0] = *(const bf16x4*)pb;
      ((bf16x4*)&bfr[j])[1] = *(const bf16x4*)(pb + 4);
    }
#pragma unroll
    for (int i = 0; i < 4; ++i)
#pragma unroll
      for (int j = 0; j < 4; ++j) acc[i][j] = mfma16(af[i], bfr[j], acc[i][j]);
  }
  __bf16* ap = attn + ((size_t)b * LLEN + lc * 256) * CCH + h * 64;
#pragma unroll
  for (int i = 0; i < 4; ++i)
#pragma unroll
    for (int j = 0; j < 4; ++j)
#pragma unroll
      for (int r = 0; r < 4; ++r) {
        int ml = w * 64 + i * 16 + lhi * 4 + r;
        int v = j * 16 + llo;
        ap[(size_t)ml * CCH + v] = (__bf16)(acc[i][j][r] * zb[ml]);
      }
}

extern "C" void kernel_launch(void* const* d_in, const int* in_sizes, int n_in,
                              void* d_out, int out_size, void* d_ws, size_t ws_size,
                              hipStream_t stream) {
  const float* x  = (const float*)d_in[0];
  const float* wq = (const float*)d_in[1];
  const float* bq = (const float*)d_in[2];
  const float* wk = (const float*)d_in[3];
  const float* bk = (const float*)d_in[4];
  const float* wv = (const float*)d_in[5];
  const float* bv = (const float*)d_in[6];
  const float* wo = (const float*)d_in[7];
  const float* bo = (const float*)d_in[8];
  float* out = (float*)d_out;

  char* p = (char*)d_ws;
  __bf16* xt    = (__bf16*)p; p += (size_t)BATCH * LLEN * CCH * 2;  // 32MB (reused as attn)
  __bf16* qt    = (__bf16*)p; p += (size_t)BATCH * LLEN * CCH * 2;  // 32MB
  __bf16* kcm   = (__bf16*)p; p += (size_t)BATCH * CCH * LLEN * 2;  // 32MB
  __bf16* vcm   = (__bf16*)p; p += (size_t)BATCH * CCH * LLEN * 2;  // 32MB
  __bf16* wqkvb = (__bf16*)p; p += (size_t)M1 * CCH * 2;
  __bf16* wob   = (__bf16*)p; p += (size_t)CCH * CCH * 2;
  float*  biasq = (float*)p;  p += (size_t)M1 * 4;
  float*  ksum  = (float*)p;  p += (size_t)BATCH * CCH * 4;
  float*  part  = (float*)p;  p += (size_t)8 * 64 * HD * HD * 4;    // 8MB
  float*  kvb   = (float*)p;  p += (size_t)64 * HD * HD * 4;        // 1MB
  float*  pks   = (float*)p;  p += (size_t)8 * 64 * 64 * 4;         // 128KB
  __bf16* attn  = xt;

  pack_w<<<1024, 256, 0, stream>>>(wq, wk, wv, wo, bq, bk, bv, wqkvb, wob, biasq);
  transpose_x<<<dim3(64, 8, BATCH), 256, 0, stream>>>(x, xt);
  gemm256x<0><<<dim3(32, 6, BATCH), 256, 0, stream>>>(wqkvb, xt, biasq, qt, kcm, vcm, nullptr);
  kv_part_k<<<dim3(8, 64), 256, 0, stream>>>(kcm, vcm, part, pks);
  red_k<<<1040, 256, 0, stream>>>(part, pks, kvb, ksum);
  apply_k<<<dim3(16, 64), 256, 0, stream>>>(qt, kvb, ksum, attn);
  gemm256x<1><<<dim3(32, 2, BATCH), 256, 0, stream>>>(wob, attn, bo, nullptr, nullptr,
                                                      nullptr, out);
}